// Round 8
// baseline (169.940 us; speedup 1.0000x reference)
//
#include <hip/hip_runtime.h>
#include <math.h>

#define B_SZ 2
#define S_SZ 2048
#define D_SZ 768
#define NH   12
#define HD   64
#define BH_T (B_SZ * NH)      // 24
#define M_TOT (B_SZ * S_SZ)   // 4096

using bfrag = __attribute__((ext_vector_type(8))) short;   // 8 bf16 (4 VGPRs)
using ffrag = __attribute__((ext_vector_type(4))) float;   // 4 fp32 acc

__device__ __forceinline__ unsigned short f2bf(float f) {      // RNE
    unsigned int u = __float_as_uint(f);
    u += 0x7fffu + ((u >> 16) & 1u);
    return (unsigned short)(u >> 16);
}
__device__ __forceinline__ unsigned short f2bf_fast(float f) { // round-half-up
    return (unsigned short)((__float_as_uint(f) + 0x8000u) >> 16);
}

// async global->LDS, 16B per lane; lds ptr must be wave-uniform base.
__device__ __forceinline__ void async16(void* lds, const void* gp) {
    __builtin_amdgcn_global_load_lds(
        (const __attribute__((address_space(1))) unsigned int*)gp,
        (__attribute__((address_space(3))) unsigned int*)lds,
        16, 0, 0);
}

// ---------------------------------------------------------------------------
// prep: fused  (a) v1 fp32->bf16   (b) W [k][n] fp32 -> Wt [n][k] bf16 x3
// ---------------------------------------------------------------------------
__global__ __launch_bounds__(256) void prep(
    const float* __restrict__ v1,
    const float* __restrict__ Wq, const float* __restrict__ Wk,
    const float* __restrict__ Wv,
    unsigned short* __restrict__ v1b, unsigned short* __restrict__ Wt) {
    __shared__ float tile[64][65];
    const int bx = blockIdx.x;
    const int t = threadIdx.x;
    if (bx < 3072) {
        int i = (bx * 256 + t) * 4;
        float4 v = *(const float4*)&v1[i];
        ushort4 o;
        o.x = f2bf(v.x); o.y = f2bf(v.y); o.z = f2bf(v.z); o.w = f2bf(v.w);
        *(ushort4*)&v1b[i] = o;
    } else {
        int r = bx - 3072;               // 0..431
        int z = r / 144;
        int rr = r % 144;
        int n0 = (rr % 12) * 64, k0 = (rr / 12) * 64;
        const float* W = (z == 0) ? Wq : (z == 1) ? Wk : Wv;
        unsigned short* dst = Wt + (size_t)z * D_SZ * D_SZ;
        #pragma unroll
        for (int i = 0; i < 16; ++i) {
            int flat = i * 256 + t;
            int rr2 = flat >> 6, c = flat & 63;
            tile[rr2][c] = W[(size_t)(k0 + rr2) * D_SZ + n0 + c];
        }
        __syncthreads();
        #pragma unroll
        for (int i = 0; i < 16; ++i) {
            int flat = i * 256 + t;
            int rr2 = flat >> 6, c = flat & 63;
            dst[(size_t)(n0 + rr2) * D_SZ + k0 + c] = f2bf(tile[c][rr2]);
        }
    }
}

// ---------------------------------------------------------------------------
// QKV projection, 32x128 tile (m x n), BK=64, single-buffered 20 KB LDS.
// Grid (6, 128, 3) = 2304 blocks = 9/CU; LDS caps at 8/CU -> high TLP to
// hide the per-iter barrier drains (the small-K latency regime fix).
// 4 waves: wm = w&1 (m-tile of 16), wn = w>>1 (n-half of 64).
// z<2 (Q,K): swapped operands -> lane holds 4 consecutive n; Q scaled 1/8.
// z==2 (V):  lane holds 4 consecutive tokens -> V stored transposed.
// ---------------------------------------------------------------------------
#define CP_LD 136   // z<2 repack: 32 rows x 128 n
#define CPV_LD 40   // z==2 repack: 128 rows x 32 m

__global__ __launch_bounds__(256) void proj_gemm(
    const unsigned short* __restrict__ Ab,    // v1 bf16 [4096][768]
    const unsigned short* __restrict__ Wt,    // [3][768 n][768 k]
    const float* __restrict__ bq, const float* __restrict__ bk_,
    const float* __restrict__ bv_,
    unsigned short* __restrict__ Qb, unsigned short* __restrict__ Kb,
    unsigned short* __restrict__ Vtb) {
    const int z = blockIdx.z;
    const unsigned short* Bt = Wt + (size_t)z * D_SZ * D_SZ;
    const float* bias = (z == 0) ? bq : (z == 1) ? bk_ : bv_;

    __shared__ unsigned short smem[32 * 64 + 128 * 64];   // 20 KB
    unsigned short* As = smem;                 // 32 x 64
    unsigned short* Bs = smem + 32 * 64;       // 128 x 64

    const int t = threadIdx.x;
    const int lane = t & 63;
    const int w = t >> 6;
    const int wm = w & 1, wn = w >> 1;
    const int col = lane & 15;
    const int quad = lane >> 4;
    const int m0 = blockIdx.y * 32;
    const int n0 = blockIdx.x * 128;
    const int wbase = t & ~63;

    ffrag acc[4];
    #pragma unroll
    for (int j = 0; j < 4; ++j) { ffrag zf = {0.f, 0.f, 0.f, 0.f}; acc[j] = zf; }

    // staging geometry
    const int arow = t >> 3, agc = ((t & 7) ^ (arow & 7)) * 8;   // A: 1/thread

    for (int k0 = 0; k0 < D_SZ; k0 += 64) {
        __syncthreads();
        async16(&As[(size_t)wbase * 8], &Ab[(size_t)(m0 + arow) * D_SZ + k0 + agc]);
        #pragma unroll
        for (int i = 0; i < 4; ++i) {
            int c = i * 256 + t;
            int row = c >> 3;
            int gcol = ((c & 7) ^ (row & 7)) * 8;
            async16(&Bs[(size_t)(i * 256 + wbase) * 8],
                    &Bt[(size_t)(n0 + row) * D_SZ + k0 + gcol]);
        }
        __syncthreads();
        #pragma unroll
        for (int kk = 0; kk < 64; kk += 32) {
            const int cc = (kk >> 3) + quad;
            bfrag a, b[4];
            {
                int row = wm * 16 + col;
                a = *(const bfrag*)&As[row * 64 + ((cc ^ (row & 7)) * 8)];
            }
            #pragma unroll
            for (int ni = 0; ni < 4; ++ni) {
                int row = wn * 64 + ni * 16 + col;
                b[ni] = *(const bfrag*)&Bs[row * 64 + ((cc ^ (row & 7)) * 8)];
            }
            if (z == 2) {
                #pragma unroll
                for (int ni = 0; ni < 4; ++ni)
                    acc[ni] = __builtin_amdgcn_mfma_f32_16x16x32_bf16(
                        a, b[ni], acc[ni], 0, 0, 0);
            } else {
                #pragma unroll
                for (int ni = 0; ni < 4; ++ni)
                    acc[ni] = __builtin_amdgcn_mfma_f32_16x16x32_bf16(
                        b[ni], a, acc[ni], 0, 0, 0);
            }
        }
    }

    __syncthreads();   // reuse smem as repack tile

    if (z < 2) {
        const float sc = (z == 0) ? 0.125f : 1.0f;   // fold 1/sqrt(hd) into Q
        const int m_local = wm * 16 + col;           // token within tile
        #pragma unroll
        for (int ni = 0; ni < 4; ++ni) {
            int n_base = wn * 64 + ni * 16 + quad * 4;     // 4 consecutive n
            float4 b4 = *(const float4*)&bias[n0 + n_base];
            uint2 pk;
            pk.x = (unsigned)f2bf((acc[ni][0] + b4.x) * sc) |
                   ((unsigned)f2bf((acc[ni][1] + b4.y) * sc) << 16);
            pk.y = (unsigned)f2bf((acc[ni][2] + b4.z) * sc) |
                   ((unsigned)f2bf((acc[ni][3] + b4.w) * sc) << 16);
            *(uint2*)&smem[m_local * CP_LD + n_base] = pk;
        }
        __syncthreads();
        unsigned short* Out = (z == 0) ? Qb : Kb;
        #pragma unroll
        for (int j = 0; j < 2; ++j) {           // 32 rows x 16 chunks
            int flat = j * 256 + t;
            int row = flat >> 4;                // token
            int ch = flat & 15;                 // 16B chunk within 128 n
            uint4 vv = *(const uint4*)&smem[row * CP_LD + ch * 8];
            int m = m0 + row;
            int bb = m >> 11, s = m & 2047;
            int h = (n0 >> 6) + (ch >> 3);
            int d = (ch & 7) * 8;
            *(uint4*)&Out[((size_t)(bb * NH + h) * S_SZ + s) * HD + d] = vv;
        }
    } else {
        #pragma unroll
        for (int ni = 0; ni < 4; ++ni) {
            int n_local = wn * 64 + ni * 16 + col;             // d index
            float bvv = bias[n0 + n_local];
            uint2 pk;
            pk.x = (unsigned)f2bf(acc[ni][0] + bvv) |
                   ((unsigned)f2bf(acc[ni][1] + bvv) << 16);
            pk.y = (unsigned)f2bf(acc[ni][2] + bvv) |
                   ((unsigned)f2bf(acc[ni][3] + bvv) << 16);
            *(uint2*)&smem[n_local * CPV_LD + wm * 16 + quad * 4] = pk;
        }
        __syncthreads();
        #pragma unroll
        for (int j = 0; j < 2; ++j) {           // 128 rows x 4 chunks
            int flat = j * 256 + t;
            int row = flat >> 2;                // n index (0..127)
            int ch = flat & 3;                  // 16B chunk within 32 tokens
            uint4 vv = *(const uint4*)&smem[row * CPV_LD + ch * 8];
            int n = n0 + row;
            int h = n >> 6, d = n & 63;
            int m = m0 + ch * 8;
            int bb = m >> 11, s = m & 2047;
            *(uint4*)&Vtb[((size_t)(bb * NH + h) * HD + d) * S_SZ + s] = vv;
        }
    }
}

// ---------------------------------------------------------------------------
// Flash attention, S^T formulation: S^T = K Q^T so the score fragment lands
// with lane: q=col, keys=quad*4+r.  P then writes to LDS as 4 packed
// ds_write_b64 (vs 16 scalar u16), mask is 4 aligned float4 loads, and the
// softmax denominator is a single scalar per lane.  64-key tiles, LDS dbuf.
// ---------------------------------------------------------------------------
__global__ __launch_bounds__(256) void attn_mfma(
    const unsigned short* __restrict__ Qb, const unsigned short* __restrict__ Kb,
    const unsigned short* __restrict__ Vt, const float* __restrict__ mask,
    float* __restrict__ out) {
    __shared__ unsigned short Ks[2][64 * 64];  // 16 KB [key][d]
    __shared__ unsigned short Vs[2][64 * 64];  // 16 KB [d][key]
    __shared__ unsigned short Ps[4][16 * 64];  // 8 KB wave-private [q][key]

    const int t = threadIdx.x;
    const int lane = t & 63;
    const int w = t >> 6;
    const int col = lane & 15;
    const int quad = lane >> 4;
    const int q0 = blockIdx.x * 64;
    const int bh = blockIdx.y;
    const int b = bh / NH, h = bh % NH;
    const int wbase = t & ~63;

    const unsigned short* Qg = Qb + (size_t)bh * S_SZ * HD;
    const unsigned short* Kg = Kb + (size_t)bh * S_SZ * HD;
    const unsigned short* Vg = Vt + (size_t)bh * S_SZ * HD;   // [hd][S]
    const float* mrow = mask + (size_t)b * S_SZ;

    // Q fragments straight global->reg (B-operand layout == A layout)
    const int arow = w * 16 + col;
    bfrag aq[2];
    #pragma unroll
    for (int kk = 0; kk < 2; ++kk)
        aq[kk] = *(const bfrag*)&Qg[(size_t)(q0 + arow) * HD + (kk * 4 + quad) * 8];

    // staging geometry (64 rows x 8 chunks, XOR swizzle)
    int srw[2], sgc[2];
    #pragma unroll
    for (int i = 0; i < 2; ++i) {
        int c = i * 256 + t;
        srw[i] = c >> 3;
        sgc[i] = ((c & 7) ^ (srw[i] & 7)) * 8;
    }

    // prologue: tile 0 into buf 0 + mask float4s
    #pragma unroll
    for (int i = 0; i < 2; ++i) {
        async16(&Ks[0][(size_t)(i * 256 + wbase) * 8],
                &Kg[(size_t)srw[i] * HD + sgc[i]]);
        async16(&Vs[0][(size_t)(i * 256 + wbase) * 8],
                &Vg[(size_t)srw[i] * S_SZ + sgc[i]]);
    }
    float4 mcur[4], mnext[4];
    #pragma unroll
    for (int ni = 0; ni < 4; ++ni)
        mcur[ni] = *(const float4*)&mrow[ni * 16 + quad * 4];

    ffrag o[4];
    #pragma unroll
    for (int i = 0; i < 4; ++i) { ffrag zf = {0.f, 0.f, 0.f, 0.f}; o[i] = zf; }
    float lsum = 0.f;

    const int nIter = S_SZ / 64;   // 32
    for (int it = 0; it < nIter; ++it) {
        const int cur = it & 1;
        __syncthreads();           // drains buf[cur] (issued during prev compute)
        if (it + 1 < nIter) {
            const int kn = (it + 1) * 64;
            #pragma unroll
            for (int i = 0; i < 2; ++i) {
                async16(&Ks[cur ^ 1][(size_t)(i * 256 + wbase) * 8],
                        &Kg[(size_t)(kn + srw[i]) * HD + sgc[i]]);
                async16(&Vs[cur ^ 1][(size_t)(i * 256 + wbase) * 8],
                        &Vg[(size_t)srw[i] * S_SZ + kn + sgc[i]]);
            }
            #pragma unroll
            for (int ni = 0; ni < 4; ++ni)
                mnext[ni] = *(const float4*)&mrow[kn + ni * 16 + quad * 4];
        }

        // S^T = K Q^T  (A = K-frag from LDS, B = Q-frag from regs)
        ffrag s[4];
        #pragma unroll
        for (int i = 0; i < 4; ++i) { ffrag zf = {0.f, 0.f, 0.f, 0.f}; s[i] = zf; }
        #pragma unroll
        for (int kk = 0; kk < 2; ++kk) {
            const int cc = kk * 4 + quad;
            #pragma unroll
            for (int ni = 0; ni < 4; ++ni) {
                int brow = ni * 16 + col;
                bfrag kf = *(const bfrag*)&Ks[cur][brow * 64 + ((cc ^ (brow & 7)) * 8)];
                s[ni] = __builtin_amdgcn_mfma_f32_16x16x32_bf16(kf, aq[kk], s[ni], 0, 0, 0);
            }
        }

        // p = exp(s + mask); scalar per-lane l (lane's q = col fixed)
        #pragma unroll
        for (int ni = 0; ni < 4; ++ni) {
            #pragma unroll
            for (int r = 0; r < 4; ++r) {
                float e = __expf(s[ni][r] + ((const float*)&mcur[ni])[r]);
                s[ni][r] = e;
                lsum += e;
            }
        }

        // P -> wave-private LDS [q][key], 4 packed 8B stores (swizzled)
        unsigned short* Pw = &Ps[w][0];
        #pragma unroll
        for (int ni = 0; ni < 4; ++ni) {
            uint2 pk;
            pk.x = (unsigned)f2bf_fast(s[ni][0]) |
                   ((unsigned)f2bf_fast(s[ni][1]) << 16);
            pk.y = (unsigned)f2bf_fast(s[ni][2]) |
                   ((unsigned)f2bf_fast(s[ni][3]) << 16);
            int phys = (((ni * 2 + (quad >> 1)) ^ (col & 7)) * 8) + ((quad & 1) * 4);
            *(uint2*)&Pw[col * 64 + phys] = pk;
        }

        // O += P @ V
        #pragma unroll
        for (int kk = 0; kk < 2; ++kk) {
            const int cc = kk * 4 + quad;
            bfrag ap = *(const bfrag*)&Pw[col * 64 + ((cc ^ (col & 7)) * 8)];
            #pragma unroll
            for (int di = 0; di < 4; ++di) {
                int vrow = di * 16 + col;
                bfrag bv8 = *(const bfrag*)&Vs[cur][vrow * 64 + ((cc ^ (vrow & 7)) * 8)];
                o[di] = __builtin_amdgcn_mfma_f32_16x16x32_bf16(ap, bv8, o[di], 0, 0, 0);
            }
        }

        #pragma unroll
        for (int ni = 0; ni < 4; ++ni) mcur[ni] = mnext[ni];
    }

    // full l for q=col via 2 shuffles; redistribute to q=quad*4+r via shfl
    lsum += __shfl_xor(lsum, 16);
    lsum += __shfl_xor(lsum, 32);
    float inv[4];
    #pragma unroll
    for (int r = 0; r < 4; ++r) inv[r] = 1.0f / __shfl(lsum, quad * 4 + r);
    #pragma unroll
    for (int di = 0; di < 4; ++di) {
        int d = di * 16 + col;
        #pragma unroll
        for (int r = 0; r < 4; ++r) {
            int q = q0 + w * 16 + quad * 4 + r;
            out[((size_t)(b * S_SZ + q)) * D_SZ + h * HD + d] = o[di][r] * inv[r];
        }
    }
}

// ---------------------------------------------------------------------------
extern "C" void kernel_launch(void* const* d_in, const int* in_sizes, int n_in,
                              void* d_out, int out_size, void* d_ws, size_t ws_size,
                              hipStream_t stream) {
    const float* v1   = (const float*)d_in[0];
    const float* mask = (const float*)d_in[1];
    const float* Wq   = (const float*)d_in[2];
    const float* bq   = (const float*)d_in[3];
    const float* Wk   = (const float*)d_in[4];
    const float* bk   = (const float*)d_in[5];
    const float* Wv   = (const float*)d_in[6];
    const float* bv   = (const float*)d_in[7];
    float* out = (float*)d_out;

    char* ws = (char*)d_ws;
    const size_t per_b = (size_t)BH_T * S_SZ * HD * 2;      // 6,291,456 B
    unsigned short* Qb  = (unsigned short*)(ws);
    unsigned short* Kb  = (unsigned short*)(ws + per_b);
    unsigned short* Vtb = (unsigned short*)(ws + 2 * per_b);
    unsigned short* v1b = (unsigned short*)(ws + 3 * per_b);
    unsigned short* Wt  = (unsigned short*)(ws + 3 * per_b + (size_t)M_TOT * D_SZ * 2);

    prep<<<dim3(3072 + 432), 256, 0, stream>>>(v1, Wq, Wk, Wv, v1b, Wt);
    proj_gemm<<<dim3(6, 128, 3), 256, 0, stream>>>(v1b, Wt, bq, bk, bv, Qb, Kb, Vtb);
    attn_mfma<<<dim3(32, 24), 256, 0, stream>>>(Qb, Kb, Vtb, mask, out);
}